// Round 18
// baseline (250.469 us; speedup 1.0000x reference)
//
#include <hip/hip_runtime.h>

// ---------------- helpers ----------------
typedef __attribute__((ext_vector_type(8))) short bf16x8;   // 8 bf16 (4 VGPRs)
typedef __attribute__((ext_vector_type(4))) float f32x4;
typedef __attribute__((ext_vector_type(2))) long i64x2;     // 16B = 2 fp8 MFMA operands

#define DEV static __device__ __forceinline__

DEV float b2f(unsigned short u) {
    union { unsigned int u; float f; } c; c.u = ((unsigned int)u) << 16; return c.f;
}
DEV unsigned short f2b(float f) {
    union { float f; unsigned int u; } c; c.f = f;
    unsigned int u = c.u + 0x7fffu + ((c.u >> 16) & 1u);
    return (unsigned short)(u >> 16);
}
DEV float silu_f(float v) { return v / (1.f + __expf(-v)); }

// hardware f32x2 -> 2x OCP e4m3 (low byte = a, high byte = b); RNE, saturating
DEV unsigned short cvtpk2(float a, float b) {
    unsigned int d;
    asm("v_cvt_pk_fp8_f32 %0, %1, %2" : "=v"(d) : "v"(a), "v"(b));
    return (unsigned short)d;
}
DEV unsigned char cvt1(float a) { return (unsigned char)cvtpk2(a, 0.f); }

// K-permutation (64-col blocks): pos(gc) — layout consumed by gemm8's LDS swizzle
DEV int kperm(int gc) {
    return (gc & ~63) | (((gc >> 3) & 3) << 4) | (((gc >> 5) & 1) << 3) | (gc & 7);
}

#define GLD16(gp, lp) __builtin_amdgcn_global_load_lds( \
    (const __attribute__((address_space(1))) void*)(gp), \
    (__attribute__((address_space(3))) void*)(lp), 16, 0, 0)

// sizes
#define LSEQ 2048
#define NB 2
#define RTOT 4096          // NB*LSEQ
#define DM 1024
#define DI 2048
#define NH 32
#define HP 64
#define NSTATE 16
#define CDIM 2080
#define DIP 4160           // per-dir in_proj width
#define NW 8320            // stacked width
#define NWP 8448           // padded to 256
#define QCH 64             // scan chunk length
#define NCH (LSEQ / QCH)   // 32 chunks

// ---------------- batched f32 -> fp8 e4m3 K-permuted convert ----------------
struct Cvt8Jobs {
    const float* s0[4];
    const float* s1[4];
    unsigned char* dst[4];
    int rows0[4], rows1[4], rowstot[4], shift[4];  // shift = log2(K/8)
};
__global__ __launch_bounds__(256) void cvt8b_kernel(Cvt8Jobs j) {
    const int jb = blockIdx.y;
    const int gid = blockIdx.x * 256 + threadIdx.x;
    const int shift = j.shift[jb];
    const int tpr = 1 << shift;
    if (gid >= (j.rowstot[jb] << shift)) return;
    const int row = gid >> shift, g = gid & (tpr - 1);
    const int blk = g >> 3, sub = g & 7, lq = sub >> 1, ks = sub & 1;
    const int K = tpr << 3;
    uint2 o;
    const int r0 = j.rows0[jb], r1 = j.rows1[jb];
    if (row < r0 + r1) {
        const float* src = (row < r0 ? j.s0[jb] + (size_t)row * K
                                     : j.s1[jb] + (size_t)(row - r0) * K)
                           + blk * 64 + ks * 32 + lq * 8;
        float4 v0 = *(const float4*)src;
        float4 v1 = *(const float4*)(src + 4);
        o.x = (unsigned)cvtpk2(v0.x, v0.y) | ((unsigned)cvtpk2(v0.z, v0.w) << 16);
        o.y = (unsigned)cvtpk2(v1.x, v1.y) | ((unsigned)cvtpk2(v1.z, v1.w) << 16);
    } else {
        o.x = 0; o.y = 0;
    }
    *(uint2*)(j.dst[jb] + (size_t)row * K + blk * 64 + sub * 8) = o;
}

// ---------------- FP8 MFMA GEMM, template <BM,BN,NBUF,EPI> ----------------
// BK=64 bytes, 8 waves (2M x 4N), NBUF LDS buffers (NBUF=2 -> 32 KB -> 4 blocks/CU),
// stage t+(NBUF-1), counted vmcnt((NBUF-2)*GT) steady-state, single barrier/K-tile.
// LDS: 128B row-pair lines, chunk XOR key (line&7). Operands K-permuted (kperm).
// EPI 1: bf16 store (col clamp at Ntot). EPI 2: f32 ex + v*esc. EPI 3: fp8 kperm store.
template<int BM, int BN, int NBUF, int EPI>
__global__ void __launch_bounds__(512, 4)
gemm8_kernel(
    const unsigned char* __restrict__ A0, const unsigned char* __restrict__ B0,
    const unsigned char* __restrict__ A1, const unsigned char* __restrict__ B1,
    void* __restrict__ Cout,
    int Ntot, int K, int ldc, int coff0, int coff1,
    const float* __restrict__ ex, const float* __restrict__ esc)
{
    constexpr int NT = 512;
    constexpr int MF = BM / 32;
    constexpr int NI = BN / 64;
    constexpr int ABYTES = BM * 64;
    constexpr int BBYTES = BN * 64;
    constexpr int BUFB = ABYTES + BBYTES;
    constexpr int QA = ABYTES / (NT * 16);
    constexpr int QB = BBYTES / (NT * 16);
    constexpr int GT = QA + QB;
    __shared__ unsigned char lds8[NBUF * BUFB];

    const unsigned char* __restrict__ A8 = blockIdx.z ? A1 : A0;
    const unsigned char* __restrict__ B8 = blockIdx.z ? B1 : B0;
    const int coff = blockIdx.z ? coff1 : coff0;

    // bijective XCD chunk + gm=8 group walk
    const int nbx = gridDim.x, nby = gridDim.y;
    const int nwg = nbx * nby;
    int id = blockIdx.y * nbx + blockIdx.x;
    {
        const int q = nwg >> 3, r = nwg & 7;
        const int xcd = id & 7, off = id >> 3;
        id = (xcd < r) ? (xcd * (q + 1) + off) : (r * (q + 1) + (xcd - r) * q + off);
    }
    const int gm = 8;
    const int gidx = id / (gm * nbx);
    const int rem  = id - gidx * gm * nbx;
    const int width = min(gm, nby - gidx * gm);
    const int bm = (gidx * gm + rem % width) * BM;
    const int bn = (rem / width) * BN;

    const int tid  = threadIdx.x;
    const int wave = tid >> 6, lane = tid & 63;
    const int wm = wave >> 2, wn = wave & 3;
    const int lr = lane & 15, lq = lane >> 4;
    const int KT = K >> 6;

    int aoff[MF], boff[NI];
#pragma unroll
    for (int mf = 0; mf < MF; ++mf) {
        int row = wm * (BM / 2) + mf * 16 + lr;
        int L = row >> 1, cc = ((row & 1) << 2) | lq;
        aoff[mf] = L * 128 + ((cc ^ (L & 7)) << 4);
    }
#pragma unroll
    for (int ni = 0; ni < NI; ++ni) {
        int row = wn * (BN / 4) + ni * 16 + lr;
        int L = row >> 1, cc = ((row & 1) << 2) | lq;
        boff[ni] = ABYTES + L * 128 + ((cc ^ (L & 7)) << 4);
    }

    auto stage = [&](int ktt, int sbuf) {
#pragma unroll
        for (int q = 0; q < QA; ++q) {
            int u = q * NT + tid;
            int L = u >> 3, cp = u & 7;
            int cc = cp ^ (L & 7);
            int srow = bm + 2 * L + (cc >> 2);
            const unsigned char* src = A8 + (size_t)srow * K + (ktt << 6) + ((cc & 3) << 4);
            GLD16(src, &lds8[sbuf * BUFB + q * (NT * 16) + (wave << 10)]);
        }
#pragma unroll
        for (int q = 0; q < QB; ++q) {
            int u = q * NT + tid;
            int L = u >> 3, cp = u & 7;
            int cc = cp ^ (L & 7);
            int srow = bn + 2 * L + (cc >> 2);
            const unsigned char* src = B8 + (size_t)srow * K + (ktt << 6) + ((cc & 3) << 4);
            GLD16(src, &lds8[sbuf * BUFB + ABYTES + q * (NT * 16) + (wave << 10)]);
        }
    };

    f32x4 acc[MF][NI];
#pragma unroll
    for (int i = 0; i < MF; ++i)
#pragma unroll
        for (int j = 0; j < NI; ++j) acc[i][j] = (f32x4){0.f, 0.f, 0.f, 0.f};

    // prologue: stage tiles 0..NBUF-2; require tile 0 resident.
    stage(0, 0);
    if constexpr (NBUF >= 3) { if (KT > 1) stage(1, 1); }
    if constexpr (NBUF >= 4) { if (KT > 2) stage(2, 2); }
    if constexpr (NBUF == 2) {
        asm volatile("s_waitcnt vmcnt(0)" ::: "memory");
    } else if constexpr (NBUF == 3) {
        if (KT > 1) { asm volatile("s_waitcnt vmcnt(%0)" :: "n"(GT) : "memory"); }
        else        { asm volatile("s_waitcnt vmcnt(0)" ::: "memory"); }
    } else {
        if (KT > 2)      { asm volatile("s_waitcnt vmcnt(%0)" :: "n"(2 * GT) : "memory"); }
        else if (KT > 1) { asm volatile("s_waitcnt vmcnt(%0)" :: "n"(GT) : "memory"); }
        else             { asm volatile("s_waitcnt vmcnt(0)" ::: "memory"); }
    }
    __builtin_amdgcn_sched_barrier(0);
    __builtin_amdgcn_s_barrier();
    __builtin_amdgcn_sched_barrier(0);

    int cur = 0, stg = NBUF - 1;
    for (int kt = 0; kt < KT; ++kt) {
        const int cb = cur * BUFB;
        if (kt + NBUF - 1 < KT) stage(kt + NBUF - 1, stg);

        i64x2 av[MF], bv[NI];
#pragma unroll
        for (int mf = 0; mf < MF; ++mf) av[mf] = *(const i64x2*)&lds8[cb + aoff[mf]];
#pragma unroll
        for (int ni = 0; ni < NI; ++ni) bv[ni] = *(const i64x2*)&lds8[cb + boff[ni]];

        __builtin_amdgcn_s_setprio(1);
#pragma unroll
        for (int mf = 0; mf < MF; ++mf)
#pragma unroll
            for (int ni = 0; ni < NI; ++ni) {
                acc[mf][ni] = __builtin_amdgcn_mfma_f32_16x16x32_fp8_fp8(av[mf].x, bv[ni].x, acc[mf][ni], 0, 0, 0);
                acc[mf][ni] = __builtin_amdgcn_mfma_f32_16x16x32_fp8_fp8(av[mf].y, bv[ni].y, acc[mf][ni], 0, 0, 0);
            }
        __builtin_amdgcn_s_setprio(0);

        if (kt + 1 < KT) {
            if constexpr (NBUF == 2) {
                asm volatile("s_waitcnt vmcnt(0)" ::: "memory");
            } else if constexpr (NBUF == 3) {
                if (kt + 2 < KT) { asm volatile("s_waitcnt vmcnt(%0)" :: "n"(GT) : "memory"); }
                else             { asm volatile("s_waitcnt vmcnt(0)" ::: "memory"); }
            } else {
                if (kt + 3 < KT)      { asm volatile("s_waitcnt vmcnt(%0)" :: "n"(2 * GT) : "memory"); }
                else if (kt + 2 < KT) { asm volatile("s_waitcnt vmcnt(%0)" :: "n"(GT) : "memory"); }
                else                  { asm volatile("s_waitcnt vmcnt(0)" ::: "memory"); }
            }
            __builtin_amdgcn_sched_barrier(0);
            __builtin_amdgcn_s_barrier();
            __builtin_amdgcn_sched_barrier(0);
        }

        cur = (cur + 1 == NBUF) ? 0 : cur + 1;
        stg = (stg + 1 == NBUF) ? 0 : stg + 1;
    }

#pragma unroll
    for (int mf = 0; mf < MF; ++mf)
#pragma unroll
        for (int ni = 0; ni < NI; ++ni)
#pragma unroll
            for (int r = 0; r < 4; ++r) {
                int grow = bm + wm * (BM / 2) + mf * 16 + lq * 4 + r;
                int gcol = bn + wn * (BN / 4) + ni * 16 + lr;
                float v = acc[mf][ni][r];
                if (EPI == 1) {
                    if (gcol < Ntot)
                        ((unsigned short*)Cout)[(size_t)grow * ldc + coff + gcol] = f2b(v);
                } else if (EPI == 2) {
                    size_t idx = (size_t)grow * ldc + gcol;
                    ((float*)Cout)[idx] = ex[idx] + v * esc[gcol];
                } else {
                    int gc = coff + gcol;
                    ((unsigned char*)Cout)[(size_t)grow * ldc + kperm(gc)] = cvt1(v);
                }
            }
}

// ---------------- depthwise conv + silu + split, with dt/dA fused ----------------
#define TCV 32
__global__ __launch_bounds__(256) void conv_kernel(
    const unsigned short* __restrict__ ZX,   // [4096][8320] bf16
    const float* __restrict__ cwF, const float* __restrict__ cbF,
    const float* __restrict__ cwB, const float* __restrict__ cbB,
    const float* __restrict__ dtbiasF, const float* __restrict__ AlogF,
    const float* __restrict__ dtbiasB, const float* __restrict__ AlogB,
    unsigned short* __restrict__ xs,         // [2][4096][2048] bf16
    float* __restrict__ Bc, float* __restrict__ Cc,
    float* __restrict__ dtb, float* __restrict__ dAb)
{
    const int c = blockIdx.x * 256 + threadIdx.x;
    const int t0 = blockIdx.y * TCV;
    const int db = blockIdx.z;
    const int d = db >> 1, b = db & 1;

    if (c >= CDIM) {                        // dt path (32 channels)
        if (c >= CDIM + NH) return;
        const int h = c - CDIM;
        const float bias = (d ? dtbiasB : dtbiasF)[h];
        const float A = -__expf((d ? AlogB : AlogF)[h]);
        const unsigned short* zp = ZX + (size_t)d * DIP + (DI + CDIM) + h;
#pragma unroll 4
        for (int i = 0; i < TCV; ++i) {
            int t = t0 + i;
            float raw = b2f(zp[((size_t)b * LSEQ + t) * NW]);
            float xv = raw + bias;
            float dtv = (xv > 20.f) ? xv : __logf(1.f + __expf(xv));
            int idx = (db * LSEQ + t) * NH + h;
            dtb[idx] = dtv;
            dAb[idx] = __expf(dtv * A);
        }
        return;
    }

    const float* cw = d ? cwB : cwF;
    const float* cb = d ? cbB : cbF;
    float4 w = *(const float4*)&cw[c * 4];
    const float bias = cb[c];
    const unsigned short* base = ZX + (size_t)d * DIP + DI + c;

    auto ldg = [&](int t) -> float {
        return (t >= 0 && t < LSEQ) ? b2f(base[(size_t)(b * LSEQ + t) * NW]) : 0.f;
    };
    auto emit = [&](int t, float acc) {
        float v = silu_f(acc);
        const int row = b * LSEQ + t;
        if (c < DI) {
            xs[((size_t)d * RTOT + row) * DI + c] = f2b(v);
        } else if (c < DI + NSTATE) {
            Bc[((size_t)db * LSEQ + t) * NSTATE + (c - DI)] = v;
        } else {
            Cc[((size_t)db * LSEQ + t) * NSTATE + (c - DI - NSTATE)] = v;
        }
    };

    if (d == 0) {
        float v0 = ldg(t0 - 3), v1 = ldg(t0 - 2), v2 = ldg(t0 - 1), vt = ldg(t0);
#pragma unroll 4
        for (int i = 0; i < TCV; ++i) {
            float vn = (i < TCV - 1) ? ldg(t0 + i + 1) : 0.f;
            emit(t0 + i, bias + w.x * v0 + w.y * v1 + w.z * v2 + w.w * vt);
            v0 = v1; v1 = v2; v2 = vt; vt = vn;
        }
    } else {
        float v3 = ldg(t0 + TCV + 2), v2 = ldg(t0 + TCV + 1), v1 = ldg(t0 + TCV), vt = ldg(t0 + TCV - 1);
#pragma unroll 4
        for (int i = TCV - 1; i >= 0; --i) {
            float vn = (i > 0) ? ldg(t0 + i - 1) : 0.f;
            emit(t0 + i, bias + w.w * vt + w.z * v1 + w.y * v2 + w.x * v3);
            v3 = v2; v2 = v1; v1 = vt; vt = vn;
        }
    }
}

#define LD16V(dst, ptr) do { const float4* _p = (const float4*)(ptr); \
    float4 _q0 = _p[0], _q1 = _p[1], _q2 = _p[2], _q3 = _p[3]; \
    dst[0]=_q0.x; dst[1]=_q0.y; dst[2]=_q0.z; dst[3]=_q0.w; \
    dst[4]=_q1.x; dst[5]=_q1.y; dst[6]=_q1.z; dst[7]=_q1.w; \
    dst[8]=_q2.x; dst[9]=_q2.y; dst[10]=_q2.z; dst[11]=_q2.w; \
    dst[12]=_q3.x; dst[13]=_q3.y; dst[14]=_q3.z; dst[15]=_q3.w; } while (0)

#define ST16V(ptr, src) do { float4* _p = (float4*)(ptr); \
    _p[0] = make_float4(src[0],src[1],src[2],src[3]); \
    _p[1] = make_float4(src[4],src[5],src[6],src[7]); \
    _p[2] = make_float4(src[8],src[9],src[10],src[11]); \
    _p[3] = make_float4(src[12],src[13],src[14],src[15]); } while (0)

// ---------------- pass A: per-chunk zero-init state + decay product ----------------
// B/dt/dA staged to LDS once per block (coalesced); steps read broadcast ds_reads.
__global__ __launch_bounds__(64) void chunk_state_kernel(
    const unsigned short* __restrict__ xs,
    const float* __restrict__ Bc,
    const float* __restrict__ dtb, const float* __restrict__ dAb,
    float* __restrict__ Sbuf,               // [128][NCH][64][16]
    float* __restrict__ Pbuf)               // [128][NCH]
{
    const int h = blockIdx.x, db = blockIdx.y, c = blockIdx.z;
    const int d = db >> 1, b = db & 1;
    const int lane = threadIdx.x;
    const size_t dbase = (size_t)d * RTOT;
    const int s0 = c * QCH;

    __shared__ float Bsh[QCH][16];
    __shared__ float dtsh[QCH], dAsh[QCH];

    // stage chunk's B (4 KB) + dt/dA (0.5 KB)
#pragma unroll
    for (int q = 0; q < 4; ++q) {
        int u = q * 64 + lane;
        int i = u >> 2, n0 = (u & 3) * 4;
        int t = d ? (LSEQ - 1 - (s0 + i)) : (s0 + i);
        size_t rdb = (size_t)db * LSEQ + t;
        *(float4*)&Bsh[i][n0] = *(const float4*)(Bc + rdb * 16 + n0);
    }
    {
        int t = d ? (LSEQ - 1 - (s0 + lane)) : (s0 + lane);
        size_t rdb = (size_t)db * LSEQ + t;
        dtsh[lane] = dtb[rdb * 32 + h];
        dAsh[lane] = dAb[rdb * 32 + h];
    }

    float hs[16];
#pragma unroll
    for (int n = 0; n < 16; ++n) hs[n] = 0.f;
    float pacc = 1.f;

    __syncthreads();

    // x prefetch depth-3
    float xq0, xq1, xq2, xq3;
#define SIDX(ii) (d ? (LSEQ - 1 - (s0 + min((ii), QCH - 1))) : (s0 + min((ii), QCH - 1)))
#define XL(S, ii) do { const int _t = SIDX(ii); \
    xq##S = b2f(xs[(dbase + (size_t)b * LSEQ + _t) * DI + h * HP + lane]); } while (0)
#define SC(S, iv) do { const float _dt = dtsh[(iv)], _dA = dAsh[(iv)]; \
    const float _dtx = _dt * xq##S; \
    _Pragma("unroll") for (int n = 0; n < 16; ++n) hs[n] = fmaf(hs[n], _dA, Bsh[(iv)][n] * _dtx); \
    pacc *= _dA; } while (0)

    XL(0, 0); XL(1, 1); XL(2, 2);
    for (int ii = 0; ii < QCH; ii += 4) {
        XL(3, ii + 3); SC(0, ii);
        XL(0, ii + 4); SC(1, ii + 1);
        XL(1, ii + 5); SC(2, ii + 2);
        XL(2, ii + 6); SC(3, ii + 3);
    }
#undef SIDX
#undef XL
#undef SC

    float* Sp = Sbuf + (((size_t)(db * NH + h)) * NCH + c) * 1024 + lane * 16;
    ST16V(Sp, hs);
    if (lane == 0) Pbuf[(db * NH + h) * NCH + c] = pacc;
}

// ---------------- pass C: combine (fused) + per-chunk scan, emit y ----------------
// B/C/dt/dA staged to LDS; combine fold covers staging latency.
__global__ __launch_bounds__(64) void chunk_scan_kernel(
    const unsigned short* __restrict__ xs,
    const float* __restrict__ Bc, const float* __restrict__ Cc,
    const float* __restrict__ dtb, const float* __restrict__ dAb,
    const float* __restrict__ DpF, const float* __restrict__ DpB,
    const float* __restrict__ Sbuf, const float* __restrict__ Pbuf,
    unsigned short* __restrict__ ybuf)       // [2][4096][2048]
{
    const int h = blockIdx.x, db = blockIdx.y, c = blockIdx.z;
    const int d = db >> 1, b = db & 1;
    const int lane = threadIdx.x;
    const float Dp = (d ? DpB : DpF)[h];
    const size_t dbase = (size_t)d * RTOT;
    const int s0 = c * QCH;

    __shared__ float Bsh[QCH][16], Csh[QCH][16];
    __shared__ float dtsh[QCH], dAsh[QCH];

    // stage chunk's B/C (8 KB) + dt/dA (0.5 KB)
#pragma unroll
    for (int q = 0; q < 4; ++q) {
        int u = q * 64 + lane;
        int i = u >> 2, n0 = (u & 3) * 4;
        int t = d ? (LSEQ - 1 - (s0 + i)) : (s0 + i);
        size_t rdb = (size_t)db * LSEQ + t;
        *(float4*)&Bsh[i][n0] = *(const float4*)(Bc + rdb * 16 + n0);
        *(float4*)&Csh[i][n0] = *(const float4*)(Cc + rdb * 16 + n0);
    }
    {
        int t = d ? (LSEQ - 1 - (s0 + lane)) : (s0 + lane);
        size_t rdb = (size_t)db * LSEQ + t;
        dtsh[lane] = dtb[rdb * 32 + h];
        dAsh[lane] = dAb[rdb * 32 + h];
    }

    // fused combine over predecessor chunks (covers staging latency)
    float hs[16];
#pragma unroll
    for (int n = 0; n < 16; ++n) hs[n] = 0.f;
    {
        const float* Sp = Sbuf + ((size_t)(db * NH + h) * NCH) * 1024 + lane * 16;
        const float* Pp = Pbuf + (db * NH + h) * NCH;
        for (int j = 0; j < c; ++j) {
            float S[16];
            LD16V(S, Sp + (size_t)j * 1024);
            const float P = Pp[j];
#pragma unroll
            for (int n = 0; n < 16; ++n) hs[n] = fmaf(hs[n], P, S[n]);
        }
    }

    __syncthreads();

    float xq0, xq1, xq2, xq3;
#define SIDX(ii) (d ? (LSEQ - 1 - (s0 + min((ii), QCH - 1))) : (s0 + min((ii), QCH - 1)))
#define XL(S, ii) do { const int _t = SIDX(ii); \
    xq##S = b2f(xs[(dbase + (size_t)b * LSEQ + _t) * DI + h * HP + lane]); } while (0)
#define SCY(S, iv) do { const float _dt = dtsh[(iv)], _dA = dAsh[(iv)]; \
    const float _dtx = _dt * xq##S; \
    float _y0 = 0.f, _y1 = 0.f, _y2 = 0.f, _y3 = 0.f; \
    _Pragma("unroll") for (int n = 0; n < 16; n += 4) { \
        hs[n]   = fmaf(hs[n],   _dA, Bsh[(iv)][n]   * _dtx); _y0 = fmaf(Csh[(iv)][n],   hs[n],   _y0); \
        hs[n+1] = fmaf(hs[n+1], _dA, Bsh[(iv)][n+1] * _dtx); _y1 = fmaf(Csh[(iv)][n+1], hs[n+1], _y1); \
        hs[n+2] = fmaf(hs[n+2], _dA, Bsh[(iv)][n+2] * _dtx); _y2 = fmaf(Csh[(iv)][n+2], hs[n+2], _y2); \
        hs[n+3] = fmaf(hs[n+3], _dA, Bsh[(iv)][n+3] * _dtx); _y3 = fmaf(Csh[(iv)][n+3], hs[n+3], _y3); } \
    const int _t = d ? (LSEQ - 1 - (s0 + (iv))) : (s0 + (iv)); \
    ybuf[(dbase + (size_t)b * LSEQ + _t) * DI + h * HP + lane] = \
        f2b(((_y0 + _y1) + (_y2 + _y3)) + Dp * xq##S); } while (0)

    XL(0, 0); XL(1, 1); XL(2, 2);
    for (int ii = 0; ii < QCH; ii += 4) {
        XL(3, ii + 3); SCY(0, ii);
        XL(0, ii + 4); SCY(1, ii + 1);
        XL(1, ii + 5); SCY(2, ii + 2);
        XL(2, ii + 6); SCY(3, ii + 3);
    }
#undef SIDX
#undef XL
#undef SCY
}

// ---------------- gate (silu(z)) + RMSNorm -> fp8 K-permuted ----------------
__global__ __launch_bounds__(256) void gatenorm_kernel(
    const unsigned short* __restrict__ ybuf, const unsigned short* __restrict__ ZX,
    const float* __restrict__ nwF, const float* __restrict__ nwB,
    unsigned char* __restrict__ yg8)        // [2][4096][2048] fp8 kperm
{
    const int r = blockIdx.x;
    const int d = blockIdx.y;
    const int tid = threadIdx.x;
    const float* nw = d ? nwB : nwF;
    const int c0 = tid * 8;
    const unsigned short* yp = ybuf + ((size_t)d * RTOT + r) * DI + c0;
    const unsigned short* zp = ZX + (size_t)r * NW + d * DIP + c0;
    uint4 yv = *(const uint4*)yp;
    uint4 zv = *(const uint4*)zp;
    unsigned int yw[4] = {yv.x, yv.y, yv.z, yv.w};
    unsigned int zw[4] = {zv.x, zv.y, zv.z, zv.w};
    float g[8]; float ss = 0.f;
#pragma unroll
    for (int i = 0; i < 8; ++i) {
        unsigned short yu = (i & 1) ? (unsigned short)(yw[i >> 1] >> 16) : (unsigned short)(yw[i >> 1] & 0xffff);
        unsigned short zu = (i & 1) ? (unsigned short)(zw[i >> 1] >> 16) : (unsigned short)(zw[i >> 1] & 0xffff);
        float y = b2f(yu), z = b2f(zu);
        float gv = y * silu_f(z);
        g[i] = gv; ss += gv * gv;
    }
#pragma unroll
    for (int m = 1; m < 64; m <<= 1) ss += __shfl_xor(ss, m, 64);
    __shared__ float red[4];
    if ((tid & 63) == 0) red[tid >> 6] = ss;
    __syncthreads();
    float tot = red[0] + red[1] + red[2] + red[3];
    float sc = rsqrtf(tot * (1.f / 2048.f) + 1e-5f);
    uint2 o;
    o.x = (unsigned)cvtpk2(g[0] * sc * nw[c0 + 0], g[1] * sc * nw[c0 + 1])
        | ((unsigned)cvtpk2(g[2] * sc * nw[c0 + 2], g[3] * sc * nw[c0 + 3]) << 16);
    o.y = (unsigned)cvtpk2(g[4] * sc * nw[c0 + 4], g[5] * sc * nw[c0 + 5])
        | ((unsigned)cvtpk2(g[6] * sc * nw[c0 + 6], g[7] * sc * nw[c0 + 7]) << 16);
    const int pos = (c0 & ~63) | (((c0 >> 3) & 3) << 4) | (((c0 >> 5) & 1) << 3);
    *(uint2*)(yg8 + ((size_t)d * RTOT + r) * DI + pos) = o;
}

// ---------------- host ----------------
extern "C" void kernel_launch(void* const* d_in, const int* in_sizes, int n_in,
                              void* d_out, int out_size, void* d_ws, size_t ws_size,
                              hipStream_t stream)
{
    const float* x     = (const float*)d_in[0];
    const float* fin   = (const float*)d_in[1];
    const float* fcw   = (const float*)d_in[2];
    const float* fcb   = (const float*)d_in[3];
    const float* fdtb  = (const float*)d_in[4];
    const float* fAlog = (const float*)d_in[5];
    const float* fDp   = (const float*)d_in[6];
    const float* fnw   = (const float*)d_in[7];
    const float* fout  = (const float*)d_in[8];
    const float* bin   = (const float*)d_in[9];
    const float* bcw   = (const float*)d_in[10];
    const float* bcb   = (const float*)d_in[11];
    const float* bdtb  = (const float*)d_in[12];
    const float* bAlog = (const float*)d_in[13];
    const float* bDp   = (const float*)d_in[14];
    const float* bnw   = (const float*)d_in[15];
    const float* bout  = (const float*)d_in[16];
    const float* lw    = (const float*)d_in[17];
    const float* lsc   = (const float*)d_in[18];

    char* w = (char*)d_ws;
    auto alloc = [&](size_t bytes) { char* p = w; w += (bytes + 255) & ~(size_t)255; return p; };
    unsigned char*  xb8  = (unsigned char*)alloc((size_t)RTOT * DM);        // 4.2 MB
    unsigned char*  win8 = (unsigned char*)alloc((size_t)NWP * DM);         // 8.65 MB
    unsigned char*  wo8  = (unsigned char*)alloc((size_t)2 * DM * DI);      // 4.2 MB
    unsigned char*  wl8  = (unsigned char*)alloc((size_t)DM * DI);          // 2.1 MB
    unsigned short* zx  = (unsigned short*)alloc((size_t)RTOT * NW * 2);    // 68 MB
    unsigned short* xs  = (unsigned short*)alloc((size_t)2 * RTOT * DI * 2);// 33.5 MB
    float* Bc  = (float*)alloc((size_t)2 * RTOT * NSTATE * 4);
    float* Cc  = (float*)alloc((size_t)2 * RTOT * NSTATE * 4);
    float* dtb = (float*)alloc((size_t)2 * RTOT * NH * 4);
    float* dAb = (float*)alloc((size_t)2 * RTOT * NH * 4);
    unsigned short* yb  = (unsigned short*)alloc((size_t)2 * RTOT * DI * 2);// 33.5 MB
    unsigned char*  yg8 = (unsigned char*)alloc((size_t)2 * RTOT * DI);     // 16.8 MB
    unsigned char*  hbi8= (unsigned char*)alloc((size_t)RTOT * DI);         // 8.4 MB
    float* Pbuf = (float*)alloc((size_t)128 * NCH * 4);
    float* Sbuf = (float*)alloc((size_t)128 * NCH * 1024 * 4);              // 16.8 MB
    (void)ws_size; (void)in_sizes; (void)n_in; (void)out_size;

    // all f32 -> fp8 K-permuted converts in ONE dispatch
    Cvt8Jobs j;
    j.s0[0] = x;    j.s1[0] = x;    j.dst[0] = xb8;  j.rows0[0] = RTOT; j.rows1[0] = 0;    j.rowstot[0] = RTOT; j.shift[0] = 7;
    j.s0[1] = fin;  j.s1[1] = bin;  j.dst[1] = win8; j.rows0[1] = DIP;  j.rows1[1] = DIP;  j.rowstot[1] = NWP;  j.shift[1] = 7;
    j.s0[2] = fout; j.s1[2] = bout; j.dst[2] = wo8;  j.rows0[2] = DM;   j.rows1[2] = DM;   j.rowstot[2] = 2 * DM; j.shift[2] = 8;
    j.s0[3] = lw;   j.s1[3] = lw;   j.dst[3] = wl8;  j.rows0[3] = DM;   j.rows1[3] = 0;    j.rowstot[3] = DM;   j.shift[3] = 8;
    cvt8b_kernel<<<dim3((NWP * 128 + 255) / 256, 4), 256, 0, stream>>>(j);

    // GEMM A (fp8): 2-buffer (32 KB LDS -> 4 blocks/CU). M=4096, N=8448(pad), K=1024.
    gemm8_kernel<128, 128, 2, 1><<<dim3(NWP / 128, RTOT / 128), 512, 0, stream>>>(
        xb8, win8, nullptr, nullptr, zx, NW, DM, NW, 0, 0, nullptr, nullptr);

    // conv + silu + split + fused dt/dA (TCV=32 -> 2304 blocks)
    conv_kernel<<<dim3((CDIM + NH + 255) / 256, LSEQ / TCV, 4), 256, 0, stream>>>(
        zx, fcw, fcb, bcw, bcb, fdtb, fAlog, bdtb, bAlog, xs, Bc, Cc, dtb, dAb);

    // chunked scan: A) per-chunk states, C) fused combine + scan + y (LDS-staged B/C/dt/dA)
    chunk_state_kernel<<<dim3(NH, 4, NCH - 1), 64, 0, stream>>>(
        xs, Bc, dtb, dAb, Sbuf, Pbuf);
    chunk_scan_kernel<<<dim3(NH, 4, NCH), 64, 0, stream>>>(
        xs, Bc, Cc, dtb, dAb, fDp, bDp, Sbuf, Pbuf, yb);

    // gate + RMSNorm -> fp8 kperm
    gatenorm_kernel<<<dim3(RTOT, 2), 256, 0, stream>>>(yb, zx, fnw, bnw, yg8);

    // GEMM B (fp8): 3-buffer <128,128>, both dirs (grid.z=2). M=4096, N=1024/dir, K=2048.
    gemm8_kernel<128, 128, 3, 3><<<dim3(DM / 128, RTOT / 128, 2), 512, 0, stream>>>(
        yg8, wo8, yg8 + (size_t)RTOT * DI, wo8 + (size_t)DM * DI,
        hbi8, DM, DI, DI, 0, DM, nullptr, nullptr);

    // GEMM C (fp8): 3-buffer <128,128> + residual epilogue. M=4096, N=1024, K=2048.
    gemm8_kernel<128, 128, 3, 2><<<dim3(DM / 128, RTOT / 128), 512, 0, stream>>>(
        hbi8, wl8, nullptr, nullptr, d_out, DM, DI, DM, 0, 0, x, lsc);
}

// Round 19
// 248.971 us; speedup vs baseline: 1.0060x; 1.0060x over previous
//
#include <hip/hip_runtime.h>

// ---------------- helpers ----------------
typedef __attribute__((ext_vector_type(8))) short bf16x8;   // 8 bf16 (4 VGPRs)
typedef __attribute__((ext_vector_type(4))) float f32x4;
typedef __attribute__((ext_vector_type(2))) long i64x2;     // 16B = 2 fp8 MFMA operands

#define DEV static __device__ __forceinline__

DEV float b2f(unsigned short u) {
    union { unsigned int u; float f; } c; c.u = ((unsigned int)u) << 16; return c.f;
}
DEV unsigned short f2b(float f) {
    union { float f; unsigned int u; } c; c.f = f;
    unsigned int u = c.u + 0x7fffu + ((c.u >> 16) & 1u);
    return (unsigned short)(u >> 16);
}
DEV float silu_f(float v) { return v / (1.f + __expf(-v)); }

// hardware f32x2 -> 2x OCP e4m3 (low byte = a, high byte = b); RNE, saturating
DEV unsigned short cvtpk2(float a, float b) {
    unsigned int d;
    asm("v_cvt_pk_fp8_f32 %0, %1, %2" : "=v"(d) : "v"(a), "v"(b));
    return (unsigned short)d;
}
DEV unsigned char cvt1(float a) { return (unsigned char)cvtpk2(a, 0.f); }

// K-permutation (64-col blocks): pos(gc) — layout consumed by gemm8's LDS swizzle
DEV int kperm(int gc) {
    return (gc & ~63) | (((gc >> 3) & 3) << 4) | (((gc >> 5) & 1) << 3) | (gc & 7);
}

#define GLD16(gp, lp) __builtin_amdgcn_global_load_lds( \
    (const __attribute__((address_space(1))) void*)(gp), \
    (__attribute__((address_space(3))) void*)(lp), 16, 0, 0)

// sizes
#define LSEQ 2048
#define NB 2
#define RTOT 4096          // NB*LSEQ
#define DM 1024
#define DI 2048
#define NH 32
#define HP 64
#define NSTATE 16
#define CDIM 2080
#define DIP 4160           // per-dir in_proj width
#define NW 8320            // stacked width
#define NWP 8448           // padded to 256
#define QCH 64             // scan chunk length
#define NCH (LSEQ / QCH)   // 32 chunks

// ---------------- batched f32 -> fp8 e4m3 K-permuted convert ----------------
struct Cvt8Jobs {
    const float* s0[4];
    const float* s1[4];
    unsigned char* dst[4];
    int rows0[4], rows1[4], rowstot[4], shift[4];  // shift = log2(K/8)
};
__global__ __launch_bounds__(256) void cvt8b_kernel(Cvt8Jobs j) {
    const int jb = blockIdx.y;
    const int gid = blockIdx.x * 256 + threadIdx.x;
    const int shift = j.shift[jb];
    const int tpr = 1 << shift;
    if (gid >= (j.rowstot[jb] << shift)) return;
    const int row = gid >> shift, g = gid & (tpr - 1);
    const int blk = g >> 3, sub = g & 7, lq = sub >> 1, ks = sub & 1;
    const int K = tpr << 3;
    uint2 o;
    const int r0 = j.rows0[jb], r1 = j.rows1[jb];
    if (row < r0 + r1) {
        const float* src = (row < r0 ? j.s0[jb] + (size_t)row * K
                                     : j.s1[jb] + (size_t)(row - r0) * K)
                           + blk * 64 + ks * 32 + lq * 8;
        float4 v0 = *(const float4*)src;
        float4 v1 = *(const float4*)(src + 4);
        o.x = (unsigned)cvtpk2(v0.x, v0.y) | ((unsigned)cvtpk2(v0.z, v0.w) << 16);
        o.y = (unsigned)cvtpk2(v1.x, v1.y) | ((unsigned)cvtpk2(v1.z, v1.w) << 16);
    } else {
        o.x = 0; o.y = 0;
    }
    *(uint2*)(j.dst[jb] + (size_t)row * K + blk * 64 + sub * 8) = o;
}

// ---------------- FP8 MFMA GEMM, template <BM,BN,NBUF,EPI> ----------------
// BK=64 bytes, 8 waves (2M x 4N), NBUF LDS buffers (NBUF=3 -> 48 KB -> 3 blocks/CU),
// stage t+(NBUF-1), counted vmcnt((NBUF-2)*GT) steady-state, single barrier/K-tile.
// LDS: 128B row-pair lines, chunk XOR key (line&7). Operands K-permuted (kperm).
// EPI 1: bf16 store (col clamp at Ntot). EPI 2: f32 ex + v*esc. EPI 3: fp8 kperm store.
template<int BM, int BN, int NBUF, int EPI>
__global__ void __launch_bounds__(512, 4)
gemm8_kernel(
    const unsigned char* __restrict__ A0, const unsigned char* __restrict__ B0,
    const unsigned char* __restrict__ A1, const unsigned char* __restrict__ B1,
    void* __restrict__ Cout,
    int Ntot, int K, int ldc, int coff0, int coff1,
    const float* __restrict__ ex, const float* __restrict__ esc)
{
    constexpr int NT = 512;
    constexpr int MF = BM / 32;
    constexpr int NI = BN / 64;
    constexpr int ABYTES = BM * 64;
    constexpr int BBYTES = BN * 64;
    constexpr int BUFB = ABYTES + BBYTES;
    constexpr int QA = ABYTES / (NT * 16);
    constexpr int QB = BBYTES / (NT * 16);
    constexpr int GT = QA + QB;
    __shared__ unsigned char lds8[NBUF * BUFB];

    const unsigned char* __restrict__ A8 = blockIdx.z ? A1 : A0;
    const unsigned char* __restrict__ B8 = blockIdx.z ? B1 : B0;
    const int coff = blockIdx.z ? coff1 : coff0;

    // bijective XCD chunk + gm=8 group walk
    const int nbx = gridDim.x, nby = gridDim.y;
    const int nwg = nbx * nby;
    int id = blockIdx.y * nbx + blockIdx.x;
    {
        const int q = nwg >> 3, r = nwg & 7;
        const int xcd = id & 7, off = id >> 3;
        id = (xcd < r) ? (xcd * (q + 1) + off) : (r * (q + 1) + (xcd - r) * q + off);
    }
    const int gm = 8;
    const int gidx = id / (gm * nbx);
    const int rem  = id - gidx * gm * nbx;
    const int width = min(gm, nby - gidx * gm);
    const int bm = (gidx * gm + rem % width) * BM;
    const int bn = (rem / width) * BN;

    const int tid  = threadIdx.x;
    const int wave = tid >> 6, lane = tid & 63;
    const int wm = wave >> 2, wn = wave & 3;
    const int lr = lane & 15, lq = lane >> 4;
    const int KT = K >> 6;

    int aoff[MF], boff[NI];
#pragma unroll
    for (int mf = 0; mf < MF; ++mf) {
        int row = wm * (BM / 2) + mf * 16 + lr;
        int L = row >> 1, cc = ((row & 1) << 2) | lq;
        aoff[mf] = L * 128 + ((cc ^ (L & 7)) << 4);
    }
#pragma unroll
    for (int ni = 0; ni < NI; ++ni) {
        int row = wn * (BN / 4) + ni * 16 + lr;
        int L = row >> 1, cc = ((row & 1) << 2) | lq;
        boff[ni] = ABYTES + L * 128 + ((cc ^ (L & 7)) << 4);
    }

    auto stage = [&](int ktt, int sbuf) {
#pragma unroll
        for (int q = 0; q < QA; ++q) {
            int u = q * NT + tid;
            int L = u >> 3, cp = u & 7;
            int cc = cp ^ (L & 7);
            int srow = bm + 2 * L + (cc >> 2);
            const unsigned char* src = A8 + (size_t)srow * K + (ktt << 6) + ((cc & 3) << 4);
            GLD16(src, &lds8[sbuf * BUFB + q * (NT * 16) + (wave << 10)]);
        }
#pragma unroll
        for (int q = 0; q < QB; ++q) {
            int u = q * NT + tid;
            int L = u >> 3, cp = u & 7;
            int cc = cp ^ (L & 7);
            int srow = bn + 2 * L + (cc >> 2);
            const unsigned char* src = B8 + (size_t)srow * K + (ktt << 6) + ((cc & 3) << 4);
            GLD16(src, &lds8[sbuf * BUFB + ABYTES + q * (NT * 16) + (wave << 10)]);
        }
    };

    f32x4 acc[MF][NI];
#pragma unroll
    for (int i = 0; i < MF; ++i)
#pragma unroll
        for (int j = 0; j < NI; ++j) acc[i][j] = (f32x4){0.f, 0.f, 0.f, 0.f};

    // prologue: stage tiles 0..NBUF-2; require tile 0 resident.
    stage(0, 0);
    if constexpr (NBUF >= 3) { if (KT > 1) stage(1, 1); }
    if constexpr (NBUF >= 4) { if (KT > 2) stage(2, 2); }
    if constexpr (NBUF == 2) {
        asm volatile("s_waitcnt vmcnt(0)" ::: "memory");
    } else if constexpr (NBUF == 3) {
        if (KT > 1) { asm volatile("s_waitcnt vmcnt(%0)" :: "n"(GT) : "memory"); }
        else        { asm volatile("s_waitcnt vmcnt(0)" ::: "memory"); }
    } else {
        if (KT > 2)      { asm volatile("s_waitcnt vmcnt(%0)" :: "n"(2 * GT) : "memory"); }
        else if (KT > 1) { asm volatile("s_waitcnt vmcnt(%0)" :: "n"(GT) : "memory"); }
        else             { asm volatile("s_waitcnt vmcnt(0)" ::: "memory"); }
    }
    __builtin_amdgcn_sched_barrier(0);
    __builtin_amdgcn_s_barrier();
    __builtin_amdgcn_sched_barrier(0);

    int cur = 0, stg = NBUF - 1;
    for (int kt = 0; kt < KT; ++kt) {
        const int cb = cur * BUFB;
        if (kt + NBUF - 1 < KT) stage(kt + NBUF - 1, stg);

        i64x2 av[MF], bv[NI];
#pragma unroll
        for (int mf = 0; mf < MF; ++mf) av[mf] = *(const i64x2*)&lds8[cb + aoff[mf]];
#pragma unroll
        for (int ni = 0; ni < NI; ++ni) bv[ni] = *(const i64x2*)&lds8[cb + boff[ni]];

        __builtin_amdgcn_s_setprio(1);
#pragma unroll
        for (int mf = 0; mf < MF; ++mf)
#pragma unroll
            for (int ni = 0; ni < NI; ++ni) {
                acc[mf][ni] = __builtin_amdgcn_mfma_f32_16x16x32_fp8_fp8(av[mf].x, bv[ni].x, acc[mf][ni], 0, 0, 0);
                acc[mf][ni] = __builtin_amdgcn_mfma_f32_16x16x32_fp8_fp8(av[mf].y, bv[ni].y, acc[mf][ni], 0, 0, 0);
            }
        __builtin_amdgcn_s_setprio(0);

        if (kt + 1 < KT) {
            if constexpr (NBUF == 2) {
                asm volatile("s_waitcnt vmcnt(0)" ::: "memory");
            } else if constexpr (NBUF == 3) {
                if (kt + 2 < KT) { asm volatile("s_waitcnt vmcnt(%0)" :: "n"(GT) : "memory"); }
                else             { asm volatile("s_waitcnt vmcnt(0)" ::: "memory"); }
            } else {
                if (kt + 3 < KT)      { asm volatile("s_waitcnt vmcnt(%0)" :: "n"(2 * GT) : "memory"); }
                else if (kt + 2 < KT) { asm volatile("s_waitcnt vmcnt(%0)" :: "n"(GT) : "memory"); }
                else                  { asm volatile("s_waitcnt vmcnt(0)" ::: "memory"); }
            }
            __builtin_amdgcn_sched_barrier(0);
            __builtin_amdgcn_s_barrier();
            __builtin_amdgcn_sched_barrier(0);
        }

        cur = (cur + 1 == NBUF) ? 0 : cur + 1;
        stg = (stg + 1 == NBUF) ? 0 : stg + 1;
    }

#pragma unroll
    for (int mf = 0; mf < MF; ++mf)
#pragma unroll
        for (int ni = 0; ni < NI; ++ni)
#pragma unroll
            for (int r = 0; r < 4; ++r) {
                int grow = bm + wm * (BM / 2) + mf * 16 + lq * 4 + r;
                int gcol = bn + wn * (BN / 4) + ni * 16 + lr;
                float v = acc[mf][ni][r];
                if (EPI == 1) {
                    if (gcol < Ntot)
                        ((unsigned short*)Cout)[(size_t)grow * ldc + coff + gcol] = f2b(v);
                } else if (EPI == 2) {
                    size_t idx = (size_t)grow * ldc + gcol;
                    ((float*)Cout)[idx] = ex[idx] + v * esc[gcol];
                } else {
                    int gc = coff + gcol;
                    ((unsigned char*)Cout)[(size_t)grow * ldc + kperm(gc)] = cvt1(v);
                }
            }
}

// ---------------- depthwise conv + silu + split, with dt/dA fused ----------------
#define TCV 32
__global__ __launch_bounds__(256) void conv_kernel(
    const unsigned short* __restrict__ ZX,   // [4096][8320] bf16
    const float* __restrict__ cwF, const float* __restrict__ cbF,
    const float* __restrict__ cwB, const float* __restrict__ cbB,
    const float* __restrict__ dtbiasF, const float* __restrict__ AlogF,
    const float* __restrict__ dtbiasB, const float* __restrict__ AlogB,
    unsigned short* __restrict__ xs,         // [2][4096][2048] bf16
    float* __restrict__ Bc, float* __restrict__ Cc,
    float* __restrict__ dtb, float* __restrict__ dAb)
{
    const int c = blockIdx.x * 256 + threadIdx.x;
    const int t0 = blockIdx.y * TCV;
    const int db = blockIdx.z;
    const int d = db >> 1, b = db & 1;

    if (c >= CDIM) {                        // dt path (32 channels)
        if (c >= CDIM + NH) return;
        const int h = c - CDIM;
        const float bias = (d ? dtbiasB : dtbiasF)[h];
        const float A = -__expf((d ? AlogB : AlogF)[h]);
        const unsigned short* zp = ZX + (size_t)d * DIP + (DI + CDIM) + h;
#pragma unroll 4
        for (int i = 0; i < TCV; ++i) {
            int t = t0 + i;
            float raw = b2f(zp[((size_t)b * LSEQ + t) * NW]);
            float xv = raw + bias;
            float dtv = (xv > 20.f) ? xv : __logf(1.f + __expf(xv));
            int idx = (db * LSEQ + t) * NH + h;
            dtb[idx] = dtv;
            dAb[idx] = __expf(dtv * A);
        }
        return;
    }

    const float* cw = d ? cwB : cwF;
    const float* cb = d ? cbB : cbF;
    float4 w = *(const float4*)&cw[c * 4];
    const float bias = cb[c];
    const unsigned short* base = ZX + (size_t)d * DIP + DI + c;

    auto ldg = [&](int t) -> float {
        return (t >= 0 && t < LSEQ) ? b2f(base[(size_t)(b * LSEQ + t) * NW]) : 0.f;
    };
    auto emit = [&](int t, float acc) {
        float v = silu_f(acc);
        const int row = b * LSEQ + t;
        if (c < DI) {
            xs[((size_t)d * RTOT + row) * DI + c] = f2b(v);
        } else if (c < DI + NSTATE) {
            Bc[((size_t)db * LSEQ + t) * NSTATE + (c - DI)] = v;
        } else {
            Cc[((size_t)db * LSEQ + t) * NSTATE + (c - DI - NSTATE)] = v;
        }
    };

    if (d == 0) {
        float v0 = ldg(t0 - 3), v1 = ldg(t0 - 2), v2 = ldg(t0 - 1), vt = ldg(t0);
#pragma unroll 4
        for (int i = 0; i < TCV; ++i) {
            float vn = (i < TCV - 1) ? ldg(t0 + i + 1) : 0.f;
            emit(t0 + i, bias + w.x * v0 + w.y * v1 + w.z * v2 + w.w * vt);
            v0 = v1; v1 = v2; v2 = vt; vt = vn;
        }
    } else {
        float v3 = ldg(t0 + TCV + 2), v2 = ldg(t0 + TCV + 1), v1 = ldg(t0 + TCV), vt = ldg(t0 + TCV - 1);
#pragma unroll 4
        for (int i = TCV - 1; i >= 0; --i) {
            float vn = (i > 0) ? ldg(t0 + i - 1) : 0.f;
            emit(t0 + i, bias + w.w * vt + w.z * v1 + w.y * v2 + w.x * v3);
            v3 = v2; v2 = v1; v1 = vt; vt = vn;
        }
    }
}

#define LD16V(dst, ptr) do { const float4* _p = (const float4*)(ptr); \
    float4 _q0 = _p[0], _q1 = _p[1], _q2 = _p[2], _q3 = _p[3]; \
    dst[0]=_q0.x; dst[1]=_q0.y; dst[2]=_q0.z; dst[3]=_q0.w; \
    dst[4]=_q1.x; dst[5]=_q1.y; dst[6]=_q1.z; dst[7]=_q1.w; \
    dst[8]=_q2.x; dst[9]=_q2.y; dst[10]=_q2.z; dst[11]=_q2.w; \
    dst[12]=_q3.x; dst[13]=_q3.y; dst[14]=_q3.z; dst[15]=_q3.w; } while (0)

#define ST16V(ptr, src) do { float4* _p = (float4*)(ptr); \
    _p[0] = make_float4(src[0],src[1],src[2],src[3]); \
    _p[1] = make_float4(src[4],src[5],src[6],src[7]); \
    _p[2] = make_float4(src[8],src[9],src[10],src[11]); \
    _p[3] = make_float4(src[12],src[13],src[14],src[15]); } while (0)

// ---------------- pass A: per-chunk zero-init state + decay product ----------------
// B/dt/dA staged to LDS once per block (coalesced); steps read broadcast ds_reads.
__global__ __launch_bounds__(64) void chunk_state_kernel(
    const unsigned short* __restrict__ xs,
    const float* __restrict__ Bc,
    const float* __restrict__ dtb, const float* __restrict__ dAb,
    float* __restrict__ Sbuf,               // [128][NCH][64][16]
    float* __restrict__ Pbuf)               // [128][NCH]
{
    const int h = blockIdx.x, db = blockIdx.y, c = blockIdx.z;
    const int d = db >> 1, b = db & 1;
    const int lane = threadIdx.x;
    const size_t dbase = (size_t)d * RTOT;
    const int s0 = c * QCH;

    __shared__ float Bsh[QCH][16];
    __shared__ float dtsh[QCH], dAsh[QCH];

    // stage chunk's B (4 KB) + dt/dA (0.5 KB)
#pragma unroll
    for (int q = 0; q < 4; ++q) {
        int u = q * 64 + lane;
        int i = u >> 2, n0 = (u & 3) * 4;
        int t = d ? (LSEQ - 1 - (s0 + i)) : (s0 + i);
        size_t rdb = (size_t)db * LSEQ + t;
        *(float4*)&Bsh[i][n0] = *(const float4*)(Bc + rdb * 16 + n0);
    }
    {
        int t = d ? (LSEQ - 1 - (s0 + lane)) : (s0 + lane);
        size_t rdb = (size_t)db * LSEQ + t;
        dtsh[lane] = dtb[rdb * 32 + h];
        dAsh[lane] = dAb[rdb * 32 + h];
    }

    float hs[16];
#pragma unroll
    for (int n = 0; n < 16; ++n) hs[n] = 0.f;
    float pacc = 1.f;

    __syncthreads();

    // x prefetch depth-3
    float xq0, xq1, xq2, xq3;
#define SIDX(ii) (d ? (LSEQ - 1 - (s0 + min((ii), QCH - 1))) : (s0 + min((ii), QCH - 1)))
#define XL(S, ii) do { const int _t = SIDX(ii); \
    xq##S = b2f(xs[(dbase + (size_t)b * LSEQ + _t) * DI + h * HP + lane]); } while (0)
#define SC(S, iv) do { const float _dt = dtsh[(iv)], _dA = dAsh[(iv)]; \
    const float _dtx = _dt * xq##S; \
    _Pragma("unroll") for (int n = 0; n < 16; ++n) hs[n] = fmaf(hs[n], _dA, Bsh[(iv)][n] * _dtx); \
    pacc *= _dA; } while (0)

    XL(0, 0); XL(1, 1); XL(2, 2);
    for (int ii = 0; ii < QCH; ii += 4) {
        XL(3, ii + 3); SC(0, ii);
        XL(0, ii + 4); SC(1, ii + 1);
        XL(1, ii + 5); SC(2, ii + 2);
        XL(2, ii + 6); SC(3, ii + 3);
    }
#undef SIDX
#undef XL
#undef SC

    float* Sp = Sbuf + (((size_t)(db * NH + h)) * NCH + c) * 1024 + lane * 16;
    ST16V(Sp, hs);
    if (lane == 0) Pbuf[(db * NH + h) * NCH + c] = pacc;
}

// ---------------- pass C: combine (fused) + per-chunk scan, emit y ----------------
// B/C/dt/dA staged to LDS; combine fold covers staging latency.
__global__ __launch_bounds__(64) void chunk_scan_kernel(
    const unsigned short* __restrict__ xs,
    const float* __restrict__ Bc, const float* __restrict__ Cc,
    const float* __restrict__ dtb, const float* __restrict__ dAb,
    const float* __restrict__ DpF, const float* __restrict__ DpB,
    const float* __restrict__ Sbuf, const float* __restrict__ Pbuf,
    unsigned short* __restrict__ ybuf)       // [2][4096][2048]
{
    const int h = blockIdx.x, db = blockIdx.y, c = blockIdx.z;
    const int d = db >> 1, b = db & 1;
    const int lane = threadIdx.x;
    const float Dp = (d ? DpB : DpF)[h];
    const size_t dbase = (size_t)d * RTOT;
    const int s0 = c * QCH;

    __shared__ float Bsh[QCH][16], Csh[QCH][16];
    __shared__ float dtsh[QCH], dAsh[QCH];

    // stage chunk's B/C (8 KB) + dt/dA (0.5 KB)
#pragma unroll
    for (int q = 0; q < 4; ++q) {
        int u = q * 64 + lane;
        int i = u >> 2, n0 = (u & 3) * 4;
        int t = d ? (LSEQ - 1 - (s0 + i)) : (s0 + i);
        size_t rdb = (size_t)db * LSEQ + t;
        *(float4*)&Bsh[i][n0] = *(const float4*)(Bc + rdb * 16 + n0);
        *(float4*)&Csh[i][n0] = *(const float4*)(Cc + rdb * 16 + n0);
    }
    {
        int t = d ? (LSEQ - 1 - (s0 + lane)) : (s0 + lane);
        size_t rdb = (size_t)db * LSEQ + t;
        dtsh[lane] = dtb[rdb * 32 + h];
        dAsh[lane] = dAb[rdb * 32 + h];
    }

    // fused combine over predecessor chunks (covers staging latency)
    float hs[16];
#pragma unroll
    for (int n = 0; n < 16; ++n) hs[n] = 0.f;
    {
        const float* Sp = Sbuf + ((size_t)(db * NH + h) * NCH) * 1024 + lane * 16;
        const float* Pp = Pbuf + (db * NH + h) * NCH;
        for (int j = 0; j < c; ++j) {
            float S[16];
            LD16V(S, Sp + (size_t)j * 1024);
            const float P = Pp[j];
#pragma unroll
            for (int n = 0; n < 16; ++n) hs[n] = fmaf(hs[n], P, S[n]);
        }
    }

    __syncthreads();

    float xq0, xq1, xq2, xq3;
#define SIDX(ii) (d ? (LSEQ - 1 - (s0 + min((ii), QCH - 1))) : (s0 + min((ii), QCH - 1)))
#define XL(S, ii) do { const int _t = SIDX(ii); \
    xq##S = b2f(xs[(dbase + (size_t)b * LSEQ + _t) * DI + h * HP + lane]); } while (0)
#define SCY(S, iv) do { const float _dt = dtsh[(iv)], _dA = dAsh[(iv)]; \
    const float _dtx = _dt * xq##S; \
    float _y0 = 0.f, _y1 = 0.f, _y2 = 0.f, _y3 = 0.f; \
    _Pragma("unroll") for (int n = 0; n < 16; n += 4) { \
        hs[n]   = fmaf(hs[n],   _dA, Bsh[(iv)][n]   * _dtx); _y0 = fmaf(Csh[(iv)][n],   hs[n],   _y0); \
        hs[n+1] = fmaf(hs[n+1], _dA, Bsh[(iv)][n+1] * _dtx); _y1 = fmaf(Csh[(iv)][n+1], hs[n+1], _y1); \
        hs[n+2] = fmaf(hs[n+2], _dA, Bsh[(iv)][n+2] * _dtx); _y2 = fmaf(Csh[(iv)][n+2], hs[n+2], _y2); \
        hs[n+3] = fmaf(hs[n+3], _dA, Bsh[(iv)][n+3] * _dtx); _y3 = fmaf(Csh[(iv)][n+3], hs[n+3], _y3); } \
    const int _t = d ? (LSEQ - 1 - (s0 + (iv))) : (s0 + (iv)); \
    ybuf[(dbase + (size_t)b * LSEQ + _t) * DI + h * HP + lane] = \
        f2b(((_y0 + _y1) + (_y2 + _y3)) + Dp * xq##S); } while (0)

    XL(0, 0); XL(1, 1); XL(2, 2);
    for (int ii = 0; ii < QCH; ii += 4) {
        XL(3, ii + 3); SCY(0, ii);
        XL(0, ii + 4); SCY(1, ii + 1);
        XL(1, ii + 5); SCY(2, ii + 2);
        XL(2, ii + 6); SCY(3, ii + 3);
    }
#undef SIDX
#undef XL
#undef SCY
}

// ---------------- gate (silu(z)) + RMSNorm -> fp8 K-permuted ----------------
__global__ __launch_bounds__(256) void gatenorm_kernel(
    const unsigned short* __restrict__ ybuf, const unsigned short* __restrict__ ZX,
    const float* __restrict__ nwF, const float* __restrict__ nwB,
    unsigned char* __restrict__ yg8)        // [2][4096][2048] fp8 kperm
{
    const int r = blockIdx.x;
    const int d = blockIdx.y;
    const int tid = threadIdx.x;
    const float* nw = d ? nwB : nwF;
    const int c0 = tid * 8;
    const unsigned short* yp = ybuf + ((size_t)d * RTOT + r) * DI + c0;
    const unsigned short* zp = ZX + (size_t)r * NW + d * DIP + c0;
    uint4 yv = *(const uint4*)yp;
    uint4 zv = *(const uint4*)zp;
    unsigned int yw[4] = {yv.x, yv.y, yv.z, yv.w};
    unsigned int zw[4] = {zv.x, zv.y, zv.z, zv.w};
    float g[8]; float ss = 0.f;
#pragma unroll
    for (int i = 0; i < 8; ++i) {
        unsigned short yu = (i & 1) ? (unsigned short)(yw[i >> 1] >> 16) : (unsigned short)(yw[i >> 1] & 0xffff);
        unsigned short zu = (i & 1) ? (unsigned short)(zw[i >> 1] >> 16) : (unsigned short)(zw[i >> 1] & 0xffff);
        float y = b2f(yu), z = b2f(zu);
        float gv = y * silu_f(z);
        g[i] = gv; ss += gv * gv;
    }
#pragma unroll
    for (int m = 1; m < 64; m <<= 1) ss += __shfl_xor(ss, m, 64);
    __shared__ float red[4];
    if ((tid & 63) == 0) red[tid >> 6] = ss;
    __syncthreads();
    float tot = red[0] + red[1] + red[2] + red[3];
    float sc = rsqrtf(tot * (1.f / 2048.f) + 1e-5f);
    uint2 o;
    o.x = (unsigned)cvtpk2(g[0] * sc * nw[c0 + 0], g[1] * sc * nw[c0 + 1])
        | ((unsigned)cvtpk2(g[2] * sc * nw[c0 + 2], g[3] * sc * nw[c0 + 3]) << 16);
    o.y = (unsigned)cvtpk2(g[4] * sc * nw[c0 + 4], g[5] * sc * nw[c0 + 5])
        | ((unsigned)cvtpk2(g[6] * sc * nw[c0 + 6], g[7] * sc * nw[c0 + 7]) << 16);
    const int pos = (c0 & ~63) | (((c0 >> 3) & 3) << 4) | (((c0 >> 5) & 1) << 3);
    *(uint2*)(yg8 + ((size_t)d * RTOT + r) * DI + pos) = o;
}

// ---------------- host ----------------
extern "C" void kernel_launch(void* const* d_in, const int* in_sizes, int n_in,
                              void* d_out, int out_size, void* d_ws, size_t ws_size,
                              hipStream_t stream)
{
    const float* x     = (const float*)d_in[0];
    const float* fin   = (const float*)d_in[1];
    const float* fcw   = (const float*)d_in[2];
    const float* fcb   = (const float*)d_in[3];
    const float* fdtb  = (const float*)d_in[4];
    const float* fAlog = (const float*)d_in[5];
    const float* fDp   = (const float*)d_in[6];
    const float* fnw   = (const float*)d_in[7];
    const float* fout  = (const float*)d_in[8];
    const float* bin   = (const float*)d_in[9];
    const float* bcw   = (const float*)d_in[10];
    const float* bcb   = (const float*)d_in[11];
    const float* bdtb  = (const float*)d_in[12];
    const float* bAlog = (const float*)d_in[13];
    const float* bDp   = (const float*)d_in[14];
    const float* bnw   = (const float*)d_in[15];
    const float* bout  = (const float*)d_in[16];
    const float* lw    = (const float*)d_in[17];
    const float* lsc   = (const float*)d_in[18];

    char* w = (char*)d_ws;
    auto alloc = [&](size_t bytes) { char* p = w; w += (bytes + 255) & ~(size_t)255; return p; };
    unsigned char*  xb8  = (unsigned char*)alloc((size_t)RTOT * DM);        // 4.2 MB
    unsigned char*  win8 = (unsigned char*)alloc((size_t)NWP * DM);         // 8.65 MB
    unsigned char*  wo8  = (unsigned char*)alloc((size_t)2 * DM * DI);      // 4.2 MB
    unsigned char*  wl8  = (unsigned char*)alloc((size_t)DM * DI);          // 2.1 MB
    unsigned short* zx  = (unsigned short*)alloc((size_t)RTOT * NW * 2);    // 68 MB
    unsigned short* xs  = (unsigned short*)alloc((size_t)2 * RTOT * DI * 2);// 33.5 MB
    float* Bc  = (float*)alloc((size_t)2 * RTOT * NSTATE * 4);
    float* Cc  = (float*)alloc((size_t)2 * RTOT * NSTATE * 4);
    float* dtb = (float*)alloc((size_t)2 * RTOT * NH * 4);
    float* dAb = (float*)alloc((size_t)2 * RTOT * NH * 4);
    unsigned short* yb  = (unsigned short*)alloc((size_t)2 * RTOT * DI * 2);// 33.5 MB
    unsigned char*  yg8 = (unsigned char*)alloc((size_t)2 * RTOT * DI);     // 16.8 MB
    unsigned char*  hbi8= (unsigned char*)alloc((size_t)RTOT * DI);         // 8.4 MB
    float* Pbuf = (float*)alloc((size_t)128 * NCH * 4);
    float* Sbuf = (float*)alloc((size_t)128 * NCH * 1024 * 4);              // 16.8 MB
    (void)ws_size; (void)in_sizes; (void)n_in; (void)out_size;

    // all f32 -> fp8 K-permuted converts in ONE dispatch
    Cvt8Jobs j;
    j.s0[0] = x;    j.s1[0] = x;    j.dst[0] = xb8;  j.rows0[0] = RTOT; j.rows1[0] = 0;    j.rowstot[0] = RTOT; j.shift[0] = 7;
    j.s0[1] = fin;  j.s1[1] = bin;  j.dst[1] = win8; j.rows0[1] = DIP;  j.rows1[1] = DIP;  j.rowstot[1] = NWP;  j.shift[1] = 7;
    j.s0[2] = fout; j.s1[2] = bout; j.dst[2] = wo8;  j.rows0[2] = DM;   j.rows1[2] = DM;   j.rowstot[2] = 2 * DM; j.shift[2] = 8;
    j.s0[3] = lw;   j.s1[3] = lw;   j.dst[3] = wl8;  j.rows0[3] = DM;   j.rows1[3] = 0;    j.rowstot[3] = DM;   j.shift[3] = 8;
    cvt8b_kernel<<<dim3((NWP * 128 + 255) / 256, 4), 256, 0, stream>>>(j);

    // GEMM A (fp8): 3-buffer (48 KB LDS -> 3 blocks/CU, proven optimum). M=4096, N=8448(pad), K=1024.
    gemm8_kernel<128, 128, 3, 1><<<dim3(NWP / 128, RTOT / 128), 512, 0, stream>>>(
        xb8, win8, nullptr, nullptr, zx, NW, DM, NW, 0, 0, nullptr, nullptr);

    // conv + silu + split + fused dt/dA (TCV=32 -> 2304 blocks)
    conv_kernel<<<dim3((CDIM + NH + 255) / 256, LSEQ / TCV, 4), 256, 0, stream>>>(
        zx, fcw, fcb, bcw, bcb, fdtb, fAlog, bdtb, bAlog, xs, Bc, Cc, dtb, dAb);

    // chunked scan: A) per-chunk states, C) fused combine + scan + y (LDS-staged B/C/dt/dA)
    chunk_state_kernel<<<dim3(NH, 4, NCH - 1), 64, 0, stream>>>(
        xs, Bc, dtb, dAb, Sbuf, Pbuf);
    chunk_scan_kernel<<<dim3(NH, 4, NCH), 64, 0, stream>>>(
        xs, Bc, Cc, dtb, dAb, fDp, bDp, Sbuf, Pbuf, yb);

    // gate + RMSNorm -> fp8 kperm
    gatenorm_kernel<<<dim3(RTOT, 2), 256, 0, stream>>>(yb, zx, fnw, bnw, yg8);

    // GEMM B (fp8): 3-buffer <128,128>, both dirs (grid.z=2). M=4096, N=1024/dir, K=2048.
    gemm8_kernel<128, 128, 3, 3><<<dim3(DM / 128, RTOT / 128, 2), 512, 0, stream>>>(
        yg8, wo8, yg8 + (size_t)RTOT * DI, wo8 + (size_t)DM * DI,
        hbi8, DM, DI, DI, 0, DM, nullptr, nullptr);

    // GEMM C (fp8): 3-buffer <128,128> + residual epilogue. M=4096, N=1024, K=2048.
    gemm8_kernel<128, 128, 3, 2><<<dim3(DM / 128, RTOT / 128), 512, 0, stream>>>(
        hbi8, wl8, nullptr, nullptr, d_out, DM, DI, DM, 0, 0, x, lsc);
}